// Round 8
// baseline (4932.900 us; speedup 1.0000x reference)
//
#include <hip/hip_runtime.h>

// DependencyParser: 2× two-layer BiLSTM (word E=512, pos P=128), T=1024, B=1,
// then rank-1 edge scores S[i][j] = H[i]@w1 + H[j]@w2 + b, diag=0.
//
// R8:
//  - R7's pin failed because the asm wasn't volatile (VGPR stayed 76 ->
//    LLVM rematerialized the weight loads inside the step loop, re-reading
//    131KB/WG/step from L2). load_pin is now asm VOLATILE: results must
//    stay VGPR-resident. Verification: VGPR_Count must jump to ~150-170.
//  - role-split waves: 768-thr word WGs. Waves 0-7 compute (R7 mapping:
//    32-lane group per h elem, w[4][4] f4v pinned, 4x ds_read_b128 + DPP
//    reduce, pub on p==16). Waves 8-11 are DEDICATED POLLERS: they spin on
//    the 8B agent-scope granules while compute runs, so the retry loop is
//    already in flight when producers land. 1 barrier/step, dbuf h_lds.
//  - exchange semantics unchanged from R2 (proven): FF-poisoned buffers,
//    agent-scope atomic 8B polls / 4B publishes (data-as-flag; h never NaN).
//  - pos unchanged from R7 (2 WGs, LDS-only recurrence), guarded for 768.

#define T_LEN 1024

typedef float f4v __attribute__((ext_vector_type(4)));

// pinned 16B load: volatile asm cannot be sunk/rematerialized/duplicated
__device__ __forceinline__ f4v load_pin(const float* a) {
  f4v v;
  asm volatile("global_load_dwordx4 %0, %1, off\n\t"
               "s_waitcnt vmcnt(0)"
               : "=v"(v) : "v"(a));
  return v;
}

// ---------------------------------------------------------------- poison ----
__global__ void poison_kernel(unsigned* p, int n) {
  int i = blockIdx.x * blockDim.x + threadIdx.x;
  int stride = gridDim.x * blockDim.x;
  for (; i < n; i += stride) p[i] = 0xFFFFFFFFu;
}

// ------------------------------------------------ GEMM C = A@W^T + b0 + b1 ----
// A: [M][K], W: [2][N][K] (z = direction), C: [2][M][N]. 64x64 tile, 256 thr.
__global__ __launch_bounds__(256) void gemm_bt(
    const float* __restrict__ A,
    const float* __restrict__ Wt,
    const float* __restrict__ B0,
    const float* __restrict__ B1,
    float* __restrict__ C,
    int M, int N, int K)
{
  const int z = blockIdx.z;
  const float* W  = Wt + (size_t)z * N * K;
  const float* b0 = B0 + (size_t)z * N;
  const float* b1 = B1 + (size_t)z * N;
  float* Cz = C + (size_t)z * M * N;

  __shared__ __align__(16) float As[16][64];
  __shared__ __align__(16) float Ws[16][64];

  const int tid = threadIdx.x;
  const int tx = tid & 15, ty = tid >> 4;
  const int brow = blockIdx.y * 64, bcol = blockIdx.x * 64;
  const int lr = tid >> 2;          // 0..63
  const int lk = (tid & 3) << 2;    // 0,4,8,12

  float acc[4][4] = {};

  for (int k0 = 0; k0 < K; k0 += 16) {
    float4 av = *(const float4*)(A + (size_t)(brow + lr) * K + k0 + lk);
    float4 wv = *(const float4*)(W + (size_t)(bcol + lr) * K + k0 + lk);
    __syncthreads();
    As[lk + 0][lr] = av.x; As[lk + 1][lr] = av.y;
    As[lk + 2][lr] = av.z; As[lk + 3][lr] = av.w;
    Ws[lk + 0][lr] = wv.x; Ws[lk + 1][lr] = wv.y;
    Ws[lk + 2][lr] = wv.z; Ws[lk + 3][lr] = wv.w;
    __syncthreads();
    #pragma unroll
    for (int kk = 0; kk < 16; ++kk) {
      float4 a = *(const float4*)&As[kk][ty << 2];
      float4 w = *(const float4*)&Ws[kk][tx << 2];
      float a4[4] = {a.x, a.y, a.z, a.w};
      float w4[4] = {w.x, w.y, w.z, w.w};
      #pragma unroll
      for (int i = 0; i < 4; ++i)
        #pragma unroll
        for (int j = 0; j < 4; ++j)
          acc[i][j] = fmaf(a4[i], w4[j], acc[i][j]);
    }
  }

  const int nb = bcol + (tx << 2);
  float bias[4];
  #pragma unroll
  for (int j = 0; j < 4; ++j) bias[j] = b0[nb + j] + b1[nb + j];
  #pragma unroll
  for (int i = 0; i < 4; ++i) {
    int m = brow + (ty << 2) + i;
    float4 out;
    out.x = acc[i][0] + bias[0];
    out.y = acc[i][1] + bias[1];
    out.z = acc[i][2] + bias[2];
    out.w = acc[i][3] + bias[3];
    *(float4*)(Cz + (size_t)m * N + nb) = out;
  }
}

// --------------------------------------------------------- fast activations ----
__device__ __forceinline__ float fsigmoid(float x) {
  return 1.f / (1.f + __expf(-x));
}
__device__ __forceinline__ float ftanh(float x) {
  return 2.f / (1.f + __expf(-2.f * x)) - 1.f;
}

// DPP add: v += dpp(v). 0xB1 xor1, 0x4E xor2, 0x141 row_half_mirror,
// 0x140 row_mirror, 0x142 row_bcast15 (32-lane total lands on p>=16).
template<int CTRL>
__device__ __forceinline__ float dpp_add(float v) {
  int x = __builtin_amdgcn_update_dpp(0, __float_as_int(v), CTRL, 0xf, 0xf, true);
  return v + __int_as_float(x);
}

// -------------------------------------------- word LSTM (role-split WG) ----
// 32 WGs x 768 thr per direction.
// Waves 0-7 (tid<512): 32-lane group owns h elem e; lane p covers cols
//   {128k+4p+j} of all 4 gate rows (wv[4][4] f4v, VOLATILE-PINNED).
//   Matvec 4x ds_read_b128 + 64 FMA, DPP-only reduce, p==16 lanes do the
//   nonlinearity and agent-scope publish of h[t][e].
// Waves 8-11 (tid>=512): dedicated pollers. Spin on one 8B granule of
//   h[t] (being produced THIS step by all WGs) and stage into
//   h_lds[(s+1)&1]. Their retry loop runs concurrently with compute.
// One __syncthreads per step; double-buffered h_lds.
__device__ __forceinline__ void word_body(
    int wg, const float* __restrict__ xg, const float* __restrict__ whh,
    float* hbuf, int rev)
{
  const int tid = threadIdx.x;

  __shared__ __align__(16) float h_lds[2][512];

  unsigned* hb = (unsigned*)hbuf;
  unsigned long long* hb64 = (unsigned long long*)hbuf;

  // ---- compute-wave setup ----
  f4v wv[4][4];
  int e = 0, p = 0;
  bool pub = false;
  float cst = 0.f;
  float xg4[4] = {0.f, 0.f, 0.f, 0.f};
  if (tid < 512) {
    const int wave = tid >> 6;
    const int lane = tid & 63;
    p = lane & 31;
    e = wg * 16 + wave * 2 + (lane >> 5);
    pub = (p == 16);
    #pragma unroll
    for (int g = 0; g < 4; ++g) {
      const float* row = whh + (size_t)(g * 512 + e) * 512 + 4 * p;
      #pragma unroll
      for (int k = 0; k < 4; ++k)
        wv[g][k] = load_pin(row + 128 * k);
    }
    if (pub) {
      const int t0 = rev ? (T_LEN - 1) : 0;
      #pragma unroll
      for (int g = 0; g < 4; ++g) xg4[g] = xg[(size_t)t0 * 2048 + g * 512 + e];
    }
    // zero-fill first h buffer
    h_lds[0][tid] = 0.f;
  }
  __syncthreads();

  for (int s = 0; s < T_LEN; ++s) {
    const int t   = rev ? (T_LEN - 1 - s) : s;
    const int buf = s & 1;

    if (tid < 512) {
      // ---- matvec: 4x ds_read_b128 + 64 FMA (weights resident) ----
      float a0 = 0.f, a1 = 0.f, a2 = 0.f, a3 = 0.f;
      #pragma unroll
      for (int k = 0; k < 4; ++k) {
        float4 hv = *(const float4*)&h_lds[buf][128 * k + 4 * p];
        float h4[4] = {hv.x, hv.y, hv.z, hv.w};
        #pragma unroll
        for (int j = 0; j < 4; ++j) {
          a0 = fmaf(wv[0][k][j], h4[j], a0);
          a1 = fmaf(wv[1][k][j], h4[j], a1);
          a2 = fmaf(wv[2][k][j], h4[j], a2);
          a3 = fmaf(wv[3][k][j], h4[j], a3);
        }
      }

      // ---- DPP-only 32-lane reduction ----
      a0 = dpp_add<0xB1>(a0);  a1 = dpp_add<0xB1>(a1);
      a2 = dpp_add<0xB1>(a2);  a3 = dpp_add<0xB1>(a3);
      a0 = dpp_add<0x4E>(a0);  a1 = dpp_add<0x4E>(a1);
      a2 = dpp_add<0x4E>(a2);  a3 = dpp_add<0x4E>(a3);
      a0 = dpp_add<0x141>(a0); a1 = dpp_add<0x141>(a1);
      a2 = dpp_add<0x141>(a2); a3 = dpp_add<0x141>(a3);
      a0 = dpp_add<0x140>(a0); a1 = dpp_add<0x140>(a1);
      a2 = dpp_add<0x140>(a2); a3 = dpp_add<0x140>(a3);
      a0 = dpp_add<0x142>(a0); a1 = dpp_add<0x142>(a1);
      a2 = dpp_add<0x142>(a2); a3 = dpp_add<0x142>(a3);

      if (pub) {
        float si = fsigmoid(a0 + xg4[0]);
        float sf = fsigmoid(a1 + xg4[1]);
        float tg = ftanh  (a2 + xg4[2]);
        float so = fsigmoid(a3 + xg4[3]);
        cst = fmaf(sf, cst, si * tg);
        float h = so * ftanh(cst);
        __hip_atomic_store(hb + (size_t)t * 512 + e, __float_as_uint(h),
                           __ATOMIC_RELAXED, __HIP_MEMORY_SCOPE_AGENT);
        if (s + 1 < T_LEN) {
          const int tn = rev ? (t - 1) : (t + 1);
          #pragma unroll
          for (int g = 0; g < 4; ++g)
            xg4[g] = xg[(size_t)tn * 2048 + g * 512 + e];
        }
      }
    } else {
      // ---- poller: stage h[t] (this step's output) into h_lds[buf^1] ----
      const int g = tid - 512;     // 0..255 granule
      unsigned long long u = __hip_atomic_load(hb64 + (size_t)t * 256 + g,
                                               __ATOMIC_RELAXED,
                                               __HIP_MEMORY_SCOPE_AGENT);
      while ((unsigned)u == 0xFFFFFFFFu || (unsigned)(u >> 32) == 0xFFFFFFFFu)
        u = __hip_atomic_load(hb64 + (size_t)t * 256 + g,
                              __ATOMIC_RELAXED, __HIP_MEMORY_SCOPE_AGENT);
      float2 v;
      v.x = __uint_as_float((unsigned)u);
      v.y = __uint_as_float((unsigned)(u >> 32));
      *(float2*)&h_lds[buf ^ 1][2 * g] = v;
    }
    __syncthreads();   // h_lds[buf^1] staged; all reads of h_lds[buf] done
  }
}

// ---------------------------------------------------- pos LSTM (single WG) ----
// H=128, one WG per direction (compute on tid<512). 4-lane group owns one
// h elem (w[4][32], unpinned); h in double-buffered LDS; 2 DPP levels;
// 1 barrier/step. Threads >=512 idle through the barriers.
__device__ __forceinline__ void pos_body(
    const float* __restrict__ xg, const float* __restrict__ whh,
    float* __restrict__ hbuf, int rev)
{
  const int tid = threadIdx.x;
  const int p   = tid & 3;
  const int e   = tid >> 2;        // valid for tid<512

  __shared__ __align__(16) float h_lds[2][128];

  float w[4][32];
  float cst = 0.f;
  float xg4[4] = {0.f, 0.f, 0.f, 0.f};
  if (tid < 512) {
    #pragma unroll
    for (int g = 0; g < 4; ++g) {
      const float* row = whh + (size_t)(g * 128 + e) * 128 + 4 * p;
      #pragma unroll
      for (int k = 0; k < 8; ++k) {
        float4 v = *(const float4*)(row + 16 * k);
        w[g][k * 4 + 0] = v.x; w[g][k * 4 + 1] = v.y;
        w[g][k * 4 + 2] = v.z; w[g][k * 4 + 3] = v.w;
      }
    }
    if (p == 0) {
      const int t0 = rev ? (T_LEN - 1) : 0;
      #pragma unroll
      for (int g = 0; g < 4; ++g) xg4[g] = xg[(size_t)t0 * 512 + g * 128 + e];
    }
  }
  if (tid < 128) h_lds[0][tid] = 0.f;
  __syncthreads();

  for (int s = 0; s < T_LEN; ++s) {
    const int t   = rev ? (T_LEN - 1 - s) : s;
    const int buf = s & 1;

    if (tid < 512) {
      float a0 = 0.f, a1 = 0.f, a2 = 0.f, a3 = 0.f;
      #pragma unroll
      for (int k = 0; k < 8; ++k) {
        float4 hv = *(const float4*)&h_lds[buf][16 * k + 4 * p];
        float h4[4] = {hv.x, hv.y, hv.z, hv.w};
        #pragma unroll
        for (int j = 0; j < 4; ++j) {
          a0 = fmaf(w[0][k * 4 + j], h4[j], a0);
          a1 = fmaf(w[1][k * 4 + j], h4[j], a1);
          a2 = fmaf(w[2][k * 4 + j], h4[j], a2);
          a3 = fmaf(w[3][k * 4 + j], h4[j], a3);
        }
      }
      a0 = dpp_add<0xB1>(a0); a1 = dpp_add<0xB1>(a1);
      a2 = dpp_add<0xB1>(a2); a3 = dpp_add<0xB1>(a3);
      a0 = dpp_add<0x4E>(a0); a1 = dpp_add<0x4E>(a1);
      a2 = dpp_add<0x4E>(a2); a3 = dpp_add<0x4E>(a3);

      if (p == 0) {
        float si = fsigmoid(a0 + xg4[0]);
        float sf = fsigmoid(a1 + xg4[1]);
        float tg = ftanh  (a2 + xg4[2]);
        float so = fsigmoid(a3 + xg4[3]);
        cst = fmaf(sf, cst, si * tg);
        float h = so * ftanh(cst);
        h_lds[buf ^ 1][e] = h;                 // next step's operand
        hbuf[(size_t)t * 128 + e] = h;         // history (plain store)
        if (s + 1 < T_LEN) {
          const int tn = rev ? (t - 1) : (t + 1);
          #pragma unroll
          for (int g = 0; g < 4; ++g)
            xg4[g] = xg[(size_t)tn * 512 + g * 128 + e];
        }
      }
    }
    __syncthreads();   // publish h_lds[buf^1] to all groups
  }
}

__global__ __launch_bounds__(768, 3) void rec_kernel(
    const float* xg_wf, const float* xg_wb, const float* whh_w,
    float* h_wf, float* h_wb,
    const float* xg_pf, const float* xg_pb, const float* whh_p,
    float* h_pf, float* h_pb)
{
  int b = blockIdx.x;
  if (b < 32)
    word_body(b, xg_wf, whh_w, h_wf, 0);
  else if (b < 64)
    word_body(b - 32, xg_wb, whh_w + 2048 * 512, h_wb, 1);
  else if (b == 64)
    pos_body(xg_pf, whh_p, h_pf, 0);
  else
    pos_body(xg_pb, whh_p + 512 * 128, h_pb, 1);
}

// ------------------------------------------------------------------ concat ----
__global__ void concat_k(const float* __restrict__ wf, const float* __restrict__ wb,
                         const float* __restrict__ pf, const float* __restrict__ pb,
                         float* __restrict__ wcat, float* __restrict__ pcat)
{
  const int totw = T_LEN * 1024;
  const int totp = T_LEN * 256;
  int idx = blockIdx.x * blockDim.x + threadIdx.x;
  int stride = gridDim.x * blockDim.x;
  for (int e = idx; e < totw + totp; e += stride) {
    if (e < totw) {
      int t = e >> 10, d = e & 1023;
      wcat[e] = d < 512 ? wf[t * 512 + d] : wb[t * 512 + (d - 512)];
    } else {
      int e2 = e - totw;
      int t = e2 >> 8, d = e2 & 255;
      pcat[e2] = d < 128 ? pf[t * 128 + d] : pb[t * 128 + (d - 128)];
    }
  }
}

// ------------------------------------------------------------- edge scores ----
__global__ __launch_bounds__(256) void edge_s(
    const float* __restrict__ hwf, const float* __restrict__ hwb,
    const float* __restrict__ hpf, const float* __restrict__ hpb,
    const float* __restrict__ ew, float* s1, float* s2)
{
  const int i = blockIdx.x;
  const int tid = threadIdx.x;
  float a1 = 0.f, a2 = 0.f;
  for (int d = tid; d < 1280; d += 256) {
    float hv;
    if (d < 512)       hv = hwf[i * 512 + d];
    else if (d < 1024) hv = hwb[i * 512 + d - 512];
    else if (d < 1152) hv = hpf[i * 128 + d - 1024];
    else               hv = hpb[i * 128 + d - 1152];
    a1 = fmaf(hv, ew[d], a1);
    a2 = fmaf(hv, ew[1280 + d], a2);
  }
  #pragma unroll
  for (int off = 32; off > 0; off >>= 1) {
    a1 += __shfl_xor(a1, off, 64);
    a2 += __shfl_xor(a2, off, 64);
  }
  __shared__ float r1[4], r2[4];
  const int wid = tid >> 6;
  if ((tid & 63) == 0) { r1[wid] = a1; r2[wid] = a2; }
  __syncthreads();
  if (tid == 0) {
    s1[i] = (r1[0] + r1[1]) + (r1[2] + r1[3]);
    s2[i] = (r2[0] + r2[1]) + (r2[2] + r2[3]);
  }
}

__global__ __launch_bounds__(256) void sfill(
    const float* __restrict__ s1, const float* __restrict__ s2,
    const float* __restrict__ eb, float* __restrict__ out)
{
  int e = blockIdx.x * 256 + threadIdx.x;  // 0 .. 1024*1024-1
  int i = e >> 10, j = e & 1023;
  out[e] = (i == j) ? 0.f : s1[i] + s2[j] + eb[0];
}

// ------------------------------------------------------------------ launch ----
extern "C" void kernel_launch(void* const* d_in, const int* in_sizes, int n_in,
                              void* d_out, int out_size, void* d_ws, size_t ws_size,
                              hipStream_t stream)
{
  const float* words   = (const float*)d_in[0];
  const float* pos     = (const float*)d_in[1];
  const float* w_w0_ih = (const float*)d_in[2];
  const float* w_w0_hh = (const float*)d_in[3];
  const float* w_b0_ih = (const float*)d_in[4];
  const float* w_b0_hh = (const float*)d_in[5];
  const float* w_w1_ih = (const float*)d_in[6];
  const float* w_w1_hh = (const float*)d_in[7];
  const float* w_b1_ih = (const float*)d_in[8];
  const float* w_b1_hh = (const float*)d_in[9];
  const float* p_w0_ih = (const float*)d_in[10];
  const float* p_w0_hh = (const float*)d_in[11];
  const float* p_b0_ih = (const float*)d_in[12];
  const float* p_b0_hh = (const float*)d_in[13];
  const float* p_w1_ih = (const float*)d_in[14];
  const float* p_w1_hh = (const float*)d_in[15];
  const float* p_b1_ih = (const float*)d_in[16];
  const float* p_b1_hh = (const float*)d_in[17];
  const float* edge_w  = (const float*)d_in[18];
  const float* edge_b  = (const float*)d_in[19];

  float* ws = (float*)d_ws;
  float* xg_w  = ws;                       // [2][1024][2048] = 4,194,304
  float* xg_p  = ws + 4194304;             // [2][1024][512]  = 1,048,576
  float* hw0_f = ws + 5242880;             // [1024][512] each (word: poisoned)
  float* hw0_b = hw0_f + 524288;
  float* hw1_f = hw0_b + 524288;
  float* hw1_b = hw1_f + 524288;
  float* hp0_f = hw1_b + 524288;           // [1024][128] each (pos: plain)
  float* hp0_b = hp0_f + 131072;
  float* hp1_f = hp0_b + 131072;
  float* hp1_b = hp1_f + 131072;
  float* wcat  = hp1_b + 131072;           // [1024][1024]
  float* pcat  = wcat + 1048576;           // [1024][256]
  float* s1    = pcat + 262144;
  float* s2    = s1 + 1024;

  // 1. poison the 4 word h buffers (data-as-flag sync); every call, since the
  //    harness does not re-poison between graph replays.
  poison_kernel<<<1024, 256, 0, stream>>>((unsigned*)hw0_f, 2097152);

  // 2. layer-0 input projections
  gemm_bt<<<dim3(32, 16, 2), 256, 0, stream>>>(words, w_w0_ih, w_b0_ih, w_b0_hh,
                                               xg_w, 1024, 2048, 512);
  gemm_bt<<<dim3(8, 16, 2), 256, 0, stream>>>(pos, p_w0_ih, p_b0_ih, p_b0_hh,
                                              xg_p, 1024, 512, 128);

  // 3. layer-0 recurrence (word f/b: 64 WGs x 768, pos f/b: 2 WGs)
  rec_kernel<<<66, 768, 0, stream>>>(xg_w, xg_w + 2097152, w_w0_hh, hw0_f, hw0_b,
                                     xg_p, xg_p + 524288, p_w0_hh, hp0_f, hp0_b);

  // 4. concat layer-0 outputs
  concat_k<<<2048, 256, 0, stream>>>(hw0_f, hw0_b, hp0_f, hp0_b, wcat, pcat);

  // 5. layer-1 input projections (xg buffers reused)
  gemm_bt<<<dim3(32, 16, 2), 256, 0, stream>>>(wcat, w_w1_ih, w_b1_ih, w_b1_hh,
                                               xg_w, 1024, 2048, 1024);
  gemm_bt<<<dim3(8, 16, 2), 256, 0, stream>>>(pcat, p_w1_ih, p_b1_ih, p_b1_hh,
                                              xg_p, 1024, 512, 256);

  // 6. layer-1 recurrence
  rec_kernel<<<66, 768, 0, stream>>>(xg_w, xg_w + 2097152, w_w1_hh, hw1_f, hw1_b,
                                     xg_p, xg_p + 524288, p_w1_hh, hp1_f, hp1_b);

  // 7. edge scores
  edge_s<<<1024, 256, 0, stream>>>(hw1_f, hw1_b, hp1_f, hp1_b, edge_w, s1, s2);
  sfill<<<4096, 256, 0, stream>>>(s1, s2, edge_b, (float*)d_out);
}

// Round 9
// 3343.205 us; speedup vs baseline: 1.4755x; 1.4755x over previous
//
#include <hip/hip_runtime.h>

// DependencyParser: 2× two-layer BiLSTM (word E=512, pos P=128), T=1024, B=1,
// then rank-1 edge scores S[i][j] = H[i]@w1 + H[j]@w2 + b, diag=0.
//
// R9 = R2's exchange protocol (proven fastest: 1620us) + R5's cheap matvec.
// Root cause of R5/R7/R8 regression vs R2 (post-R8 evidence): scattered
// 8-wave publish (256 store events/step chip-wide) vs R2's single-wave
// coalesced 64B store (32 events). Consumers wait on the max event -> the
// issue spread lands on the serial chain every step.
// Structure per step (word):
//   [tid<256: poll 8B agent granule -> h_lds]  B1
//   [all: 4x ds_read_b128 + 64 FMA, DPP reduce; p==16: hgates[e]=float4]  B2
//   [tid<16: hgates + xg bias -> nonlin (cstate lane-resident) ->
//    ONE coalesced 64B agent publish; prefetch next xg]
// pos: R7's single-WG LDS recurrence (unchanged).

#define T_LEN 1024

// ---------------------------------------------------------------- poison ----
__global__ void poison_kernel(unsigned* p, int n) {
  int i = blockIdx.x * blockDim.x + threadIdx.x;
  int stride = gridDim.x * blockDim.x;
  for (; i < n; i += stride) p[i] = 0xFFFFFFFFu;
}

// ------------------------------------------------ GEMM C = A@W^T + b0 + b1 ----
// A: [M][K], W: [2][N][K] (z = direction), C: [2][M][N]. 64x64 tile, 256 thr.
__global__ __launch_bounds__(256) void gemm_bt(
    const float* __restrict__ A,
    const float* __restrict__ Wt,
    const float* __restrict__ B0,
    const float* __restrict__ B1,
    float* __restrict__ C,
    int M, int N, int K)
{
  const int z = blockIdx.z;
  const float* W  = Wt + (size_t)z * N * K;
  const float* b0 = B0 + (size_t)z * N;
  const float* b1 = B1 + (size_t)z * N;
  float* Cz = C + (size_t)z * M * N;

  __shared__ __align__(16) float As[16][64];
  __shared__ __align__(16) float Ws[16][64];

  const int tid = threadIdx.x;
  const int tx = tid & 15, ty = tid >> 4;
  const int brow = blockIdx.y * 64, bcol = blockIdx.x * 64;
  const int lr = tid >> 2;          // 0..63
  const int lk = (tid & 3) << 2;    // 0,4,8,12

  float acc[4][4] = {};

  for (int k0 = 0; k0 < K; k0 += 16) {
    float4 av = *(const float4*)(A + (size_t)(brow + lr) * K + k0 + lk);
    float4 wv = *(const float4*)(W + (size_t)(bcol + lr) * K + k0 + lk);
    __syncthreads();
    As[lk + 0][lr] = av.x; As[lk + 1][lr] = av.y;
    As[lk + 2][lr] = av.z; As[lk + 3][lr] = av.w;
    Ws[lk + 0][lr] = wv.x; Ws[lk + 1][lr] = wv.y;
    Ws[lk + 2][lr] = wv.z; Ws[lk + 3][lr] = wv.w;
    __syncthreads();
    #pragma unroll
    for (int kk = 0; kk < 16; ++kk) {
      float4 a = *(const float4*)&As[kk][ty << 2];
      float4 w = *(const float4*)&Ws[kk][tx << 2];
      float a4[4] = {a.x, a.y, a.z, a.w};
      float w4[4] = {w.x, w.y, w.z, w.w};
      #pragma unroll
      for (int i = 0; i < 4; ++i)
        #pragma unroll
        for (int j = 0; j < 4; ++j)
          acc[i][j] = fmaf(a4[i], w4[j], acc[i][j]);
    }
  }

  const int nb = bcol + (tx << 2);
  float bias[4];
  #pragma unroll
  for (int j = 0; j < 4; ++j) bias[j] = b0[nb + j] + b1[nb + j];
  #pragma unroll
  for (int i = 0; i < 4; ++i) {
    int m = brow + (ty << 2) + i;
    float4 out;
    out.x = acc[i][0] + bias[0];
    out.y = acc[i][1] + bias[1];
    out.z = acc[i][2] + bias[2];
    out.w = acc[i][3] + bias[3];
    *(float4*)(Cz + (size_t)m * N + nb) = out;
  }
}

// --------------------------------------------------------- fast activations ----
__device__ __forceinline__ float fsigmoid(float x) {
  return 1.f / (1.f + __expf(-x));
}
__device__ __forceinline__ float ftanh(float x) {
  return 2.f / (1.f + __expf(-2.f * x)) - 1.f;
}

// DPP add: v += dpp(v). 0xB1 xor1, 0x4E xor2, 0x141 row_half_mirror,
// 0x140 row_mirror, 0x142 row_bcast15 (32-lane total lands on p>=16).
template<int CTRL>
__device__ __forceinline__ float dpp_add(float v) {
  int x = __builtin_amdgcn_update_dpp(0, __float_as_int(v), CTRL, 0xf, 0xf, true);
  return v + __int_as_float(x);
}

// ---------------------------------------- word LSTM (R2 exchange, R5 math) ----
// 32 WGs x 512 thr per direction. 32-lane group owns one h elem: lane p
// covers cols {128k+4p+j} of all 4 gate rows (w[4][4] float4).
// Exchange identical to R2: tid<256 poll one 8B granule of h_prev via
// agent-scope atomic load (FF-poison = not-ready; h never NaN) into h_lds;
// publish is ONE coalesced 64B agent store from lanes 0-15 of wave 0.
__device__ __forceinline__ void word_body(
    int wg, const float* __restrict__ xg, const float* __restrict__ whh,
    float* hbuf, int rev)
{
  const int tid  = threadIdx.x;
  const int wave = tid >> 6;
  const int lane = tid & 63;
  const int p    = lane & 31;
  const int half = lane >> 5;
  const int eloc = wave * 2 + half;      // 0..15
  const int e    = wg * 16 + eloc;       // global h element 0..511

  // wv[g][k] = whh[g*512+e][128k + 4p .. +3]
  float4 wv[4][4];
  #pragma unroll
  for (int g = 0; g < 4; ++g) {
    const float* row = whh + (size_t)(g * 512 + e) * 512 + 4 * p;
    #pragma unroll
    for (int k = 0; k < 4; ++k)
      wv[g][k] = *(const float4*)(row + 128 * k);
  }

  __shared__ __align__(16) float h_lds[512];
  __shared__ __align__(16) float4 hgates[16];   // [eloc] = {i,f,g,o} sums

  unsigned* hb = (unsigned*)hbuf;
  unsigned long long* hb64 = (unsigned long long*)hbuf;

  // tail state (lanes 0-15 of wave 0): cstate + xg bias pipeline
  const bool tail = (tid < 16);
  float cst = 0.f;
  float xg4[4] = {0.f, 0.f, 0.f, 0.f};
  if (tail) {
    const int t0 = rev ? (T_LEN - 1) : 0;
    #pragma unroll
    for (int g = 0; g < 4; ++g)
      xg4[g] = xg[(size_t)t0 * 2048 + g * 512 + wg * 16 + tid];
  }

  for (int s = 0; s < T_LEN; ++s) {
    const int t = rev ? (T_LEN - 1 - s) : s;

    // ---- stage h_prev into LDS (256 pollers x 8B, R2-proven) ----
    if (tid < 256) {
      float2 v;
      if (s == 0) {
        v.x = 0.f; v.y = 0.f;
      } else {
        const int tp = rev ? (t + 1) : (t - 1);
        unsigned long long u = __hip_atomic_load(hb64 + (size_t)tp * 256 + tid,
                                                 __ATOMIC_RELAXED,
                                                 __HIP_MEMORY_SCOPE_AGENT);
        while ((unsigned)u == 0xFFFFFFFFu || (unsigned)(u >> 32) == 0xFFFFFFFFu)
          u = __hip_atomic_load(hb64 + (size_t)tp * 256 + tid,
                                __ATOMIC_RELAXED, __HIP_MEMORY_SCOPE_AGENT);
        v.x = __uint_as_float((unsigned)u);
        v.y = __uint_as_float((unsigned)(u >> 32));
      }
      *(float2*)&h_lds[2 * tid] = v;
    }
    __syncthreads();   // B1: h_lds ready; prev hgates consumed

    // ---- matvec: 4x ds_read_b128 + 64 FMA ----
    float a0 = 0.f, a1 = 0.f, a2 = 0.f, a3 = 0.f;
    #pragma unroll
    for (int k = 0; k < 4; ++k) {
      float4 hv = *(const float4*)&h_lds[128 * k + 4 * p];
      float h4[4] = {hv.x, hv.y, hv.z, hv.w};
      #pragma unroll
      for (int j = 0; j < 4; ++j) {
        a0 = fmaf(wv[0][k].x * 0.f + ((const float*)&wv[0][k])[j], h4[j], a0);
        a1 = fmaf(((const float*)&wv[1][k])[j], h4[j], a1);
        a2 = fmaf(((const float*)&wv[2][k])[j], h4[j], a2);
        a3 = fmaf(((const float*)&wv[3][k])[j], h4[j], a3);
      }
    }

    // ---- DPP-only 32-lane reduction (totals land on p>=16) ----
    a0 = dpp_add<0xB1>(a0);  a1 = dpp_add<0xB1>(a1);
    a2 = dpp_add<0xB1>(a2);  a3 = dpp_add<0xB1>(a3);
    a0 = dpp_add<0x4E>(a0);  a1 = dpp_add<0x4E>(a1);
    a2 = dpp_add<0x4E>(a2);  a3 = dpp_add<0x4E>(a3);
    a0 = dpp_add<0x141>(a0); a1 = dpp_add<0x141>(a1);
    a2 = dpp_add<0x141>(a2); a3 = dpp_add<0x141>(a3);
    a0 = dpp_add<0x140>(a0); a1 = dpp_add<0x140>(a1);
    a2 = dpp_add<0x140>(a2); a3 = dpp_add<0x140>(a3);
    a0 = dpp_add<0x142>(a0); a1 = dpp_add<0x142>(a1);
    a2 = dpp_add<0x142>(a2); a3 = dpp_add<0x142>(a3);

    if (p == 16) {
      float4 gsum; gsum.x = a0; gsum.y = a1; gsum.z = a2; gsum.w = a3;
      hgates[eloc] = gsum;
    }
    __syncthreads();   // B2: hgates ready

    // ---- tail: nonlin + ONE coalesced 64B publish (lanes 0-15) ----
    if (tail) {
      float4 g4 = hgates[tid];
      float si = fsigmoid(g4.x + xg4[0]);
      float sf = fsigmoid(g4.y + xg4[1]);
      float tg = ftanh  (g4.z + xg4[2]);
      float so = fsigmoid(g4.w + xg4[3]);
      cst = fmaf(sf, cst, si * tg);
      float h = so * ftanh(cst);
      __hip_atomic_store(hb + (size_t)t * 512 + wg * 16 + tid,
                         __float_as_uint(h),
                         __ATOMIC_RELAXED, __HIP_MEMORY_SCOPE_AGENT);
      // prefetch next step's xg bias (hidden under next poll + matvec)
      if (s + 1 < T_LEN) {
        const int tn = rev ? (t - 1) : (t + 1);
        #pragma unroll
        for (int g = 0; g < 4; ++g)
          xg4[g] = xg[(size_t)tn * 2048 + g * 512 + wg * 16 + tid];
      }
    }
    // next poll (after loop top) writes h_lds only post-B2 -> safe.
  }
}

// ---------------------------------------------------- pos LSTM (single WG) ----
// H=128, one 512-thr WG per direction. 4-lane group owns one h elem
// (w[4][32]); h in double-buffered LDS; 2 DPP levels; 1 barrier/step.
__device__ __forceinline__ void pos_body(
    const float* __restrict__ xg, const float* __restrict__ whh,
    float* __restrict__ hbuf, int rev)
{
  const int tid = threadIdx.x;
  const int p   = tid & 3;
  const int e   = tid >> 2;        // 0..127

  float w[4][32];
  #pragma unroll
  for (int g = 0; g < 4; ++g) {
    const float* row = whh + (size_t)(g * 128 + e) * 128 + 4 * p;
    #pragma unroll
    for (int k = 0; k < 8; ++k) {
      float4 v = *(const float4*)(row + 16 * k);
      w[g][k * 4 + 0] = v.x; w[g][k * 4 + 1] = v.y;
      w[g][k * 4 + 2] = v.z; w[g][k * 4 + 3] = v.w;
    }
  }

  __shared__ __align__(16) float h_lds[2][128];

  float cst = 0.f;
  float xg4[4] = {0.f, 0.f, 0.f, 0.f};
  if (p == 0) {
    const int t0 = rev ? (T_LEN - 1) : 0;
    #pragma unroll
    for (int g = 0; g < 4; ++g) xg4[g] = xg[(size_t)t0 * 512 + g * 128 + e];
  }
  if (tid < 128) h_lds[0][tid] = 0.f;
  __syncthreads();

  for (int s = 0; s < T_LEN; ++s) {
    const int t   = rev ? (T_LEN - 1 - s) : s;
    const int buf = s & 1;

    float a0 = 0.f, a1 = 0.f, a2 = 0.f, a3 = 0.f;
    #pragma unroll
    for (int k = 0; k < 8; ++k) {
      float4 hv = *(const float4*)&h_lds[buf][16 * k + 4 * p];
      float h4[4] = {hv.x, hv.y, hv.z, hv.w};
      #pragma unroll
      for (int j = 0; j < 4; ++j) {
        a0 = fmaf(w[0][k * 4 + j], h4[j], a0);
        a1 = fmaf(w[1][k * 4 + j], h4[j], a1);
        a2 = fmaf(w[2][k * 4 + j], h4[j], a2);
        a3 = fmaf(w[3][k * 4 + j], h4[j], a3);
      }
    }
    a0 = dpp_add<0xB1>(a0); a1 = dpp_add<0xB1>(a1);
    a2 = dpp_add<0xB1>(a2); a3 = dpp_add<0xB1>(a3);
    a0 = dpp_add<0x4E>(a0); a1 = dpp_add<0x4E>(a1);
    a2 = dpp_add<0x4E>(a2); a3 = dpp_add<0x4E>(a3);

    if (p == 0) {
      float si = fsigmoid(a0 + xg4[0]);
      float sf = fsigmoid(a1 + xg4[1]);
      float tg = ftanh  (a2 + xg4[2]);
      float so = fsigmoid(a3 + xg4[3]);
      cst = fmaf(sf, cst, si * tg);
      float h = so * ftanh(cst);
      h_lds[buf ^ 1][e] = h;                 // next step's operand
      hbuf[(size_t)t * 128 + e] = h;         // history (plain store)
      if (s + 1 < T_LEN) {
        const int tn = rev ? (t - 1) : (t + 1);
        #pragma unroll
        for (int g = 0; g < 4; ++g)
          xg4[g] = xg[(size_t)tn * 512 + g * 128 + e];
      }
    }
    __syncthreads();   // publish h_lds[buf^1] to all groups
  }
}

__global__ __launch_bounds__(512, 1) void rec_kernel(
    const float* xg_wf, const float* xg_wb, const float* whh_w,
    float* h_wf, float* h_wb,
    const float* xg_pf, const float* xg_pb, const float* whh_p,
    float* h_pf, float* h_pb)
{
  int b = blockIdx.x;
  if (b < 32)
    word_body(b, xg_wf, whh_w, h_wf, 0);
  else if (b < 64)
    word_body(b - 32, xg_wb, whh_w + 2048 * 512, h_wb, 1);
  else if (b == 64)
    pos_body(xg_pf, whh_p, h_pf, 0);
  else
    pos_body(xg_pb, whh_p + 512 * 128, h_pb, 1);
}

// ------------------------------------------------------------------ concat ----
__global__ void concat_k(const float* __restrict__ wf, const float* __restrict__ wb,
                         const float* __restrict__ pf, const float* __restrict__ pb,
                         float* __restrict__ wcat, float* __restrict__ pcat)
{
  const int totw = T_LEN * 1024;
  const int totp = T_LEN * 256;
  int idx = blockIdx.x * blockDim.x + threadIdx.x;
  int stride = gridDim.x * blockDim.x;
  for (int e = idx; e < totw + totp; e += stride) {
    if (e < totw) {
      int t = e >> 10, d = e & 1023;
      wcat[e] = d < 512 ? wf[t * 512 + d] : wb[t * 512 + (d - 512)];
    } else {
      int e2 = e - totw;
      int t = e2 >> 8, d = e2 & 255;
      pcat[e2] = d < 128 ? pf[t * 128 + d] : pb[t * 128 + (d - 128)];
    }
  }
}

// ------------------------------------------------------------- edge scores ----
__global__ __launch_bounds__(256) void edge_s(
    const float* __restrict__ hwf, const float* __restrict__ hwb,
    const float* __restrict__ hpf, const float* __restrict__ hpb,
    const float* __restrict__ ew, float* s1, float* s2)
{
  const int i = blockIdx.x;
  const int tid = threadIdx.x;
  float a1 = 0.f, a2 = 0.f;
  for (int d = tid; d < 1280; d += 256) {
    float hv;
    if (d < 512)       hv = hwf[i * 512 + d];
    else if (d < 1024) hv = hwb[i * 512 + d - 512];
    else if (d < 1152) hv = hpf[i * 128 + d - 1024];
    else               hv = hpb[i * 128 + d - 1152];
    a1 = fmaf(hv, ew[d], a1);
    a2 = fmaf(hv, ew[1280 + d], a2);
  }
  #pragma unroll
  for (int off = 32; off > 0; off >>= 1) {
    a1 += __shfl_xor(a1, off, 64);
    a2 += __shfl_xor(a2, off, 64);
  }
  __shared__ float r1[4], r2[4];
  const int wid = tid >> 6;
  if ((tid & 63) == 0) { r1[wid] = a1; r2[wid] = a2; }
  __syncthreads();
  if (tid == 0) {
    s1[i] = (r1[0] + r1[1]) + (r1[2] + r1[3]);
    s2[i] = (r2[0] + r2[1]) + (r2[2] + r2[3]);
  }
}

__global__ __launch_bounds__(256) void sfill(
    const float* __restrict__ s1, const float* __restrict__ s2,
    const float* __restrict__ eb, float* __restrict__ out)
{
  int e = blockIdx.x * 256 + threadIdx.x;  // 0 .. 1024*1024-1
  int i = e >> 10, j = e & 1023;
  out[e] = (i == j) ? 0.f : s1[i] + s2[j] + eb[0];
}

// ------------------------------------------------------------------ launch ----
extern "C" void kernel_launch(void* const* d_in, const int* in_sizes, int n_in,
                              void* d_out, int out_size, void* d_ws, size_t ws_size,
                              hipStream_t stream)
{
  const float* words   = (const float*)d_in[0];
  const float* pos     = (const float*)d_in[1];
  const float* w_w0_ih = (const float*)d_in[2];
  const float* w_w0_hh = (const float*)d_in[3];
  const float* w_b0_ih = (const float*)d_in[4];
  const float* w_b0_hh = (const float*)d_in[5];
  const float* w_w1_ih = (const float*)d_in[6];
  const float* w_w1_hh = (const float*)d_in[7];
  const float* w_b1_ih = (const float*)d_in[8];
  const float* w_b1_hh = (const float*)d_in[9];
  const float* p_w0_ih = (const float*)d_in[10];
  const float* p_w0_hh = (const float*)d_in[11];
  const float* p_b0_ih = (const float*)d_in[12];
  const float* p_b0_hh = (const float*)d_in[13];
  const float* p_w1_ih = (const float*)d_in[14];
  const float* p_w1_hh = (const float*)d_in[15];
  const float* p_b1_ih = (const float*)d_in[16];
  const float* p_b1_hh = (const float*)d_in[17];
  const float* edge_w  = (const float*)d_in[18];
  const float* edge_b  = (const float*)d_in[19];

  float* ws = (float*)d_ws;
  float* xg_w  = ws;                       // [2][1024][2048] = 4,194,304
  float* xg_p  = ws + 4194304;             // [2][1024][512]  = 1,048,576
  float* hw0_f = ws + 5242880;             // [1024][512] each (word: poisoned)
  float* hw0_b = hw0_f + 524288;
  float* hw1_f = hw0_b + 524288;
  float* hw1_b = hw1_f + 524288;
  float* hp0_f = hw1_b + 524288;           // [1024][128] each (pos: plain)
  float* hp0_b = hp0_f + 131072;
  float* hp1_f = hp0_b + 131072;
  float* hp1_b = hp1_f + 131072;
  float* wcat  = hp1_b + 131072;           // [1024][1024]
  float* pcat  = wcat + 1048576;           // [1024][256]
  float* s1    = pcat + 262144;
  float* s2    = s1 + 1024;

  // 1. poison the 4 word h buffers (data-as-flag sync); every call, since the
  //    harness does not re-poison between graph replays.
  poison_kernel<<<1024, 256, 0, stream>>>((unsigned*)hw0_f, 2097152);

  // 2. layer-0 input projections
  gemm_bt<<<dim3(32, 16, 2), 256, 0, stream>>>(words, w_w0_ih, w_b0_ih, w_b0_hh,
                                               xg_w, 1024, 2048, 512);
  gemm_bt<<<dim3(8, 16, 2), 256, 0, stream>>>(pos, p_w0_ih, p_b0_ih, p_b0_hh,
                                              xg_p, 1024, 512, 128);

  // 3. layer-0 recurrence (word f/b: 64 WGs, pos f/b: 2 WGs)
  rec_kernel<<<66, 512, 0, stream>>>(xg_w, xg_w + 2097152, w_w0_hh, hw0_f, hw0_b,
                                     xg_p, xg_p + 524288, p_w0_hh, hp0_f, hp0_b);

  // 4. concat layer-0 outputs
  concat_k<<<2048, 256, 0, stream>>>(hw0_f, hw0_b, hp0_f, hp0_b, wcat, pcat);

  // 5. layer-1 input projections (xg buffers reused)
  gemm_bt<<<dim3(32, 16, 2), 256, 0, stream>>>(wcat, w_w1_ih, w_b1_ih, w_b1_hh,
                                               xg_w, 1024, 2048, 1024);
  gemm_bt<<<dim3(8, 16, 2), 256, 0, stream>>>(pcat, p_w1_ih, p_b1_ih, p_b1_hh,
                                              xg_p, 1024, 512, 256);

  // 6. layer-1 recurrence
  rec_kernel<<<66, 512, 0, stream>>>(xg_w, xg_w + 2097152, w_w1_hh, hw1_f, hw1_b,
                                     xg_p, xg_p + 524288, p_w1_hh, hp1_f, hp1_b);

  // 7. edge scores
  edge_s<<<1024, 256, 0, stream>>>(hw1_f, hw1_b, hp1_f, hp1_b, edge_w, s1, s2);
  sfill<<<4096, 256, 0, stream>>>(s1, s2, edge_b, (float*)d_out);
}